// Round 27
// baseline (108.719 us; speedup 1.0000x reference)
//
#include <hip/hip_runtime.h>
#include <hip/hip_bf16.h>
#include <cstdint>
#include <cstddef>

typedef __attribute__((ext_vector_type(8))) short bf16x8;
typedef __attribute__((ext_vector_type(4))) float f32x4;
typedef __attribute__((ext_vector_type(16))) float f32x16;

#define SCALE2 0.180336880111112f   // 0.125 * log2(e): softmax in base-2 domain
#define VSTRIDE 2080                // V^T row stride (padded: 4160B = 65 cache lines)

__device__ __forceinline__ unsigned short f2bf(float f) {
    unsigned u = __builtin_bit_cast(unsigned, f);
    unsigned r = (u + 0x7FFFu + ((u >> 16) & 1u)) >> 16;
    return (unsigned short)r;
}

__device__ __forceinline__ void gload16(const unsigned short* g, unsigned short* l) {
    __builtin_amdgcn_global_load_lds(
        (const __attribute__((address_space(1))) unsigned int*)(g),
        (__attribute__((address_space(3))) unsigned int*)(l), 16, 0, 0);
}

// ---------------- merged f32 -> bf16 convert (x + 4 weights) ----------------
__global__ void cvt_all(const float* __restrict__ x,
                        const float* __restrict__ wq, const float* __restrict__ wk,
                        const float* __restrict__ wv, const float* __restrict__ wo,
                        unsigned short* __restrict__ xb,
                        unsigned short* __restrict__ wqb, unsigned short* __restrict__ wkb,
                        unsigned short* __restrict__ wvb, unsigned short* __restrict__ wob)
{
    const int y = blockIdx.y;
    const float* src; unsigned short* dst; int n;
    switch (y) {
        case 0: src = x;  dst = xb;  n = 4194304; break;
        case 1: src = wq; dst = wqb; n = 1048576; break;
        case 2: src = wk; dst = wkb; n = 1048576; break;
        case 3: src = wv; dst = wvb; n = 1048576; break;
        default: src = wo; dst = wob; n = 1048576; break;
    }
    const int i = (blockIdx.x * 256 + threadIdx.x) * 4;
    if (i < n) {
        float4 v = *(const float4*)(src + i);
        ushort4 o;
        o.x = f2bf(v.x); o.y = f2bf(v.y); o.z = f2bf(v.z); o.w = f2bf(v.w);
        *(ushort4*)(dst + i) = o;
    }
}

// ---------------- QKV projection GEMM + bias + RoPE (512 thr, pipelined) -------------
// (unchanged from r25/r26)
__global__ __launch_bounds__(512) void gemm_qkv(
    const unsigned short* __restrict__ xb,
    const unsigned short* __restrict__ wqb,
    const unsigned short* __restrict__ wkb,
    const unsigned short* __restrict__ wvb,
    const float* __restrict__ bq, const float* __restrict__ bk, const float* __restrict__ bv,
    const float* __restrict__ cosT, const float* __restrict__ sinT,
    unsigned short* __restrict__ Qb, unsigned short* __restrict__ Kb, unsigned short* __restrict__ Vtg)
{
    const int bid = blockIdx.x;
    const int xcd = bid & 7;
    const int s = bid >> 3;               // 0..95
    const int i4 = xcd >> 1, k2 = xcd & 1;
    const int z = s >> 5;                 // 0..2
    const int tt = s & 31;                // 0..31
    const int m0 = (i4 * 8 + (tt >> 2)) * 128;
    const int n0 = (k2 * 4 + (tt & 3)) * 128;

    const unsigned short* wb = (z == 0) ? wqb : ((z == 1) ? wkb : wvb);
    const float* bias = (z == 0) ? bq : ((z == 1) ? bk : bv);
    unsigned short* dst = (z == 0) ? Qb : Kb;

    __shared__ __align__(16) unsigned char gsm[49152];   // 3 x (8KB A + 8KB B); Ct alias

    const int tid = threadIdx.x;
    const int lane = tid & 63;
    const int w = tid >> 6;               // 0..7
    const int wr = w >> 2, wc = w & 3;    // 2 x 4 wave grid
    const int lr = lane & 15, lg = lane >> 4;
    const int srow = tid >> 2;            // 0..127
    const int sslot = (tid & 3) ^ (srow & 3);   // pre-swizzled source seg
    const int wdst = (tid & ~63) * 8;           // wave-uniform LDS dest (elements)

    f32x4 acc[4][2] = {};

#define GSTAGE(KK, B)                                                                  \
    {                                                                                  \
        unsigned short* ab_ = (unsigned short*)(gsm + (B) * 16384);                    \
        unsigned short* bb_ = ab_ + 4096;                                              \
        gload16(xb + (size_t)(m0 + srow) * 1024 + (KK) * 32 + sslot * 8, ab_ + wdst);  \
        gload16(wb + (size_t)(n0 + srow) * 1024 + (KK) * 32 + sslot * 8, bb_ + wdst);  \
    }

    GSTAGE(0, 0);
    GSTAGE(1, 1);
    int bsel = 0;
    for (int kk = 0; kk < 32; ++kk) {
        if (kk < 31) asm volatile("s_waitcnt vmcnt(2)" ::: "memory");
        else         asm volatile("s_waitcnt vmcnt(0)" ::: "memory");
        __syncthreads();                       // buf[bsel] staged for all waves
        if (kk + 2 < 32) {
            int b2 = bsel + 2; if (b2 >= 3) b2 -= 3;
            GSTAGE(kk + 2, b2);
        }
        const unsigned short* Al = (const unsigned short*)(gsm + bsel * 16384);
        const unsigned short* Bl = Al + 4096;
        bf16x8 af[4], bfr[2];
#pragma unroll
        for (int mt = 0; mt < 4; ++mt) {
            const int row = wr * 64 + mt * 16 + lr;
            af[mt] = *(const bf16x8*)(Al + row * 32 + (lg ^ (row & 3)) * 8);
        }
#pragma unroll
        for (int nt = 0; nt < 2; ++nt) {
            const int row = wc * 32 + nt * 16 + lr;
            bfr[nt] = *(const bf16x8*)(Bl + row * 32 + (lg ^ (row & 3)) * 8);
        }
        __builtin_amdgcn_s_setprio(1);
#pragma unroll
        for (int mt = 0; mt < 4; ++mt)
#pragma unroll
            for (int nt = 0; nt < 2; ++nt)
                acc[mt][nt] = __builtin_amdgcn_mfma_f32_16x16x32_bf16(af[mt], bfr[nt], acc[mt][nt], 0, 0, 0);
        __builtin_amdgcn_s_setprio(0);
        bsel += 1; if (bsel == 3) bsel = 0;
    }

    // ---- epilogue: regs -> Ct (aliased over staging LDS), coalesced stores ----
    unsigned short* Ct = (unsigned short*)gsm;   // 128 x 136 = 34 KB <= 48 KB
    __syncthreads();                             // all staging reads done
#pragma unroll
    for (int mt = 0; mt < 4; ++mt) {
#pragma unroll
        for (int nt = 0; nt < 2; ++nt) {
            const int coln = wc * 32 + nt * 16 + lr;     // 0..127
            const int col = n0 + coln;
            const float bcol = bias[col];
            const int hd = col & 63;
#pragma unroll
            for (int r = 0; r < 4; ++r) {
                const int rowm = wr * 64 + mt * 16 + lg * 4 + r;   // 0..127
                float v = acc[mt][nt][r] + bcol;
                if (z < 2) {
                    float part = __shfl_xor(v, 1);   // partner col (hd^1), same row
                    const int ttm = (m0 + rowm) & 2047;
                    const int i = hd >> 1;
                    const float cc = cosT[ttm * 32 + i], ss = sinT[ttm * 32 + i];
                    v = (hd & 1) ? (part * ss + v * cc) : (v * cc - part * ss);
                    if (z == 0) v *= SCALE2;
                    Ct[rowm * 136 + coln] = f2bf(v);
                } else {
                    Ct[coln * 136 + rowm] = f2bf(v);   // transposed for V^T store
                }
            }
        }
    }
    __syncthreads();
    if (z < 2) {
#pragma unroll
        for (int p = 0; p < 4; ++p) {
            const int u = p * 512 + tid;                 // < 2048
            const int row = u >> 4, seg = u & 15;
            bf16x8 vv = *(const bf16x8*)(Ct + row * 136 + seg * 8);
            const int mrow = m0 + row;
            const int ttm = mrow & 2047, bb = mrow >> 11;
            const int col = n0 + seg * 8;
            const int h = col >> 6, hd = col & 63;
            *(bf16x8*)(dst + ((size_t)(bb * 16 + h) * 2048 + ttm) * 64 + hd) = vv;
        }
    } else {
        const int bb = m0 >> 11;
#pragma unroll
        for (int p = 0; p < 4; ++p) {
            const int u = p * 512 + tid;                 // < 2048
            const int vrow = u >> 4, seg = u & 15;
            bf16x8 vv = *(const bf16x8*)(Ct + vrow * 136 + seg * 8);
            const int col = n0 + vrow;
            const int h = col >> 6, hd = col & 63;
            const int ttm = (m0 + seg * 8) & 2047;
            *(bf16x8*)(Vtg + ((size_t)(bb * 16 + h) * 64 + hd) * VSTRIDE + ttm) = vv;
        }
    }
#undef GSTAGE
}

// ---------------- Flash attention (causal): quad-chunk blocks + MFMA row-sum --------
// r26 structure (3-deep pipeline) with the softmax denominator computed by MFMA:
// smacc += ones(32x16) @ P^T per k-slice — every output row of ones@P^T equals the
// kv-sum, and C-layout reg 0 holds a valid row for both lane halves, so all 64 lanes
// read the running total in smacc[0]. Deletes the 15-add VALU tree per tile and the
// final cross-half shuffle; denominator now uses the same bf16-rounded P as PV.
__global__ __launch_bounds__(512) void attn_fwd(
    const unsigned short* __restrict__ Qb, const unsigned short* __restrict__ Kb,
    const unsigned short* __restrict__ Vtg, unsigned short* __restrict__ attnb)
{
    __shared__ __align__(16) unsigned char smem[65536];  // 4 x (8KB K + 8KB V)

    const int tid = threadIdx.x, lane = tid & 63, w = tid >> 6;
    const int l31 = lane & 31, lh = lane >> 5;
    const int bid = blockIdx.x;
    const int bh = bid & 31;
    const int g = bid >> 5;                  // 0..15
    const int cidx = w >> 1;                 // 0..3
    const int slice = w & 1;                 // tile parity within super
    const int c = (cidx == 0) ? (63 - g) : ((cidx == 1) ? (47 - g) : ((cidx == 2) ? (16 + g) : g));
    const int smax = (63 - g) >> 1;          // block-wide super count driver
    const size_t base = (size_t)bh * 131072;
    const int myq = c * 32 + l31;

    const unsigned short* Kg = Kb + base;
    const unsigned short* Vg = Vtg + (size_t)bh * (64 * VSTRIDE);

    bf16x8 qf[4];
#pragma unroll
    for (int s = 0; s < 4; ++s)
        qf[s] = *(const bf16x8*)(Qb + base + (size_t)myq * 64 + s * 16 + lh * 8);

    bf16x8 ones;
#pragma unroll
    for (int j = 0; j < 8; ++j) ones[j] = (short)0x3F80;   // 1.0 bf16

    f32x16 o0 = {}, o1 = {}, smacc = {};

    // STAGE super-tile S: 512 threads, 1 K-load + 1 V-load each (16B), pre-swizzled src.
#define STAGE(S, B)                                                                   \
    {                                                                                 \
        unsigned short* kb_ = (unsigned short*)(smem + (B) * 16384);                  \
        unsigned short* vb_ = (unsigned short*)(smem + (B) * 16384 + 8192);           \
        const int row = tid >> 3, ss = (tid & 7) ^ (row & 7);                         \
        gload16(Kg + (size_t)((S) * 64 + row) * 64 + ss * 8, kb_ + (tid & ~63) * 8);  \
        gload16(Vg + (size_t)row * VSTRIDE + (S) * 64 + ss * 8, vb_ + (tid & ~63) * 8);\
    }

    STAGE(0, 0);
    STAGE(1, 1);
    if (smax >= 2) STAGE(2, 2);
    for (int s = 0; s <= smax; ++s) {
        if (s + 2 <= smax)      asm volatile("s_waitcnt vmcnt(4)" ::: "memory");
        else if (s + 1 <= smax) asm volatile("s_waitcnt vmcnt(2)" ::: "memory");
        else                    asm volatile("s_waitcnt vmcnt(0)" ::: "memory");
        __syncthreads();                       // buf[s&3] ready for all waves
        if (s + 3 <= smax) STAGE(s + 3, (s + 3) & 3);
        const int t = 2 * s + slice;
        if (t <= c) {
            const unsigned short* Kc = (const unsigned short*)(smem + (s & 3) * 16384);
            const unsigned short* Vc = Kc + 4096;   // +8192 bytes (element pointer)
            const int kvb = t * 32;
            const int sw = l31 & 7;
            const int roff = slice * 32 + l31;

            bf16x8 kf0 = *(const bf16x8*)(Kc + roff * 64 + ((0 + lh) ^ sw) * 8);
            bf16x8 kf1 = *(const bf16x8*)(Kc + roff * 64 + ((2 + lh) ^ sw) * 8);
            bf16x8 kf2 = *(const bf16x8*)(Kc + roff * 64 + ((4 + lh) ^ sw) * 8);
            bf16x8 kf3 = *(const bf16x8*)(Kc + roff * 64 + ((6 + lh) ^ sw) * 8);

            f32x16 st = {};
            __builtin_amdgcn_s_setprio(1);
            st = __builtin_amdgcn_mfma_f32_32x32x16_bf16(kf0, qf[0], st, 0, 0, 0);
            st = __builtin_amdgcn_mfma_f32_32x32x16_bf16(kf1, qf[1], st, 0, 0, 0);
            st = __builtin_amdgcn_mfma_f32_32x32x16_bf16(kf2, qf[2], st, 0, 0, 0);
            st = __builtin_amdgcn_mfma_f32_32x32x16_bf16(kf3, qf[3], st, 0, 0, 0);
            __builtin_amdgcn_s_setprio(0);

            if (t == c) {
#pragma unroll
                for (int r = 0; r < 16; ++r) {
                    const int kv = kvb + (r & 3) + 8 * (r >> 2) + 4 * lh;
                    st[r] = (kv <= myq) ? st[r] : -1e30f;
                }
            }
#pragma unroll
            for (int r = 0; r < 16; ++r) st[r] = exp2f(st[r]);

            unsigned pw0, pw1, pw2, pw3, pw4, pw5, pw6, pw7;
            {
                unsigned a0, a1, b0, b1;
                asm("v_cvt_pk_bf16_f32 %0, %1, %2" : "=v"(a0) : "v"(st[0]), "v"(st[1]));
                asm("v_cvt_pk_bf16_f32 %0, %1, %2" : "=v"(a1) : "v"(st[2]), "v"(st[3]));
                asm("v_cvt_pk_bf16_f32 %0, %1, %2" : "=v"(b0) : "v"(st[4]), "v"(st[5]));
                asm("v_cvt_pk_bf16_f32 %0, %1, %2" : "=v"(b1) : "v"(st[6]), "v"(st[7]));
                asm("v_permlane32_swap_b32 %0, %1" : "+v"(a0), "+v"(b0));
                asm("v_permlane32_swap_b32 %0, %1" : "+v"(a1), "+v"(b1));
                pw0 = a0; pw1 = a1; pw2 = b0; pw3 = b1;
            }
            {
                unsigned a0, a1, b0, b1;
                asm("v_cvt_pk_bf16_f32 %0, %1, %2" : "=v"(a0) : "v"(st[8]), "v"(st[9]));
                asm("v_cvt_pk_bf16_f32 %0, %1, %2" : "=v"(a1) : "v"(st[10]), "v"(st[11]));
                asm("v_cvt_pk_bf16_f32 %0, %1, %2" : "=v"(b0) : "v"(st[12]), "v"(st[13]));
                asm("v_cvt_pk_bf16_f32 %0, %1, %2" : "=v"(b1) : "v"(st[14]), "v"(st[15]));
                asm("v_permlane32_swap_b32 %0, %1" : "+v"(a0), "+v"(b0));
                asm("v_permlane32_swap_b32 %0, %1" : "+v"(a1), "+v"(b1));
                pw4 = a0; pw5 = a1; pw6 = b0; pw7 = b1;
            }

            const int vs0 = (slice * 4 + lh) ^ sw;
            const int vs1 = (slice * 4 + 2 + lh) ^ sw;
            bf16x8 vf00 = *(const bf16x8*)(Vc + l31 * 64 + vs0 * 8);
            bf16x8 vf01 = *(const bf16x8*)(Vc + l31 * 64 + vs1 * 8);
            bf16x8 vf10 = *(const bf16x8*)(Vc + (32 + l31) * 64 + vs0 * 8);
            bf16x8 vf11 = *(const bf16x8*)(Vc + (32 + l31) * 64 + vs1 * 8);

            uint4 h0 = make_uint4(pw0, pw1, pw2, pw3);
            uint4 h1 = make_uint4(pw4, pw5, pw6, pw7);
            bf16x8 pf0 = __builtin_bit_cast(bf16x8, h0);
            bf16x8 pf1 = __builtin_bit_cast(bf16x8, h1);
            __builtin_amdgcn_s_setprio(1);
            o0 = __builtin_amdgcn_mfma_f32_32x32x16_bf16(vf00, pf0, o0, 0, 0, 0);
            o1 = __builtin_amdgcn_mfma_f32_32x32x16_bf16(vf10, pf0, o1, 0, 0, 0);
            smacc = __builtin_amdgcn_mfma_f32_32x32x16_bf16(ones, pf0, smacc, 0, 0, 0);
            o0 = __builtin_amdgcn_mfma_f32_32x32x16_bf16(vf01, pf1, o0, 0, 0, 0);
            o1 = __builtin_amdgcn_mfma_f32_32x32x16_bf16(vf11, pf1, o1, 0, 0, 0);
            smacc = __builtin_amdgcn_mfma_f32_32x32x16_bf16(ones, pf1, smacc, 0, 0, 0);
            __builtin_amdgcn_s_setprio(0);
        }
    }

    const float sm = smacc[0];   // every lane: row (4*lh) of ones@P^T = full kv-sum

    // ---- per-chunk partner-slice sum-merge (staging LDS re-aliased) ----
    float* Om = (float*)smem;                 // [4][32][64] = 32 KB
    float* Ms = (float*)(smem + 32768);       // [4][64]
    __syncthreads();                          // all staging reads/writes done
    if (slice == 1) {
#pragma unroll
        for (int i = 0; i < 16; ++i) Om[(cidx * 32 + i) * 64 + lane] = o0[i];
#pragma unroll
        for (int i = 0; i < 16; ++i) Om[(cidx * 32 + 16 + i) * 64 + lane] = o1[i];
        Ms[cidx * 64 + lane] = sm;
    }
    __syncthreads();
    if (slice == 0) {
        const float s = sm + Ms[cidx * 64 + lane];
        const float inv = 1.f / s;
        const int b = bh >> 4, h = bh & 15;
        unsigned short* obase = attnb + ((size_t)(b * 2048 + myq)) * 1024 + h * 64;
#pragma unroll
        for (int gg = 0; gg < 4; ++gg) {
            ushort4 u;
            u.x = f2bf((o0[gg * 4 + 0] + Om[(cidx * 32 + gg * 4 + 0) * 64 + lane]) * inv);
            u.y = f2bf((o0[gg * 4 + 1] + Om[(cidx * 32 + gg * 4 + 1) * 64 + lane]) * inv);
            u.z = f2bf((o0[gg * 4 + 2] + Om[(cidx * 32 + gg * 4 + 2) * 64 + lane]) * inv);
            u.w = f2bf((o0[gg * 4 + 3] + Om[(cidx * 32 + gg * 4 + 3) * 64 + lane]) * inv);
            *(ushort4*)(obase + gg * 8 + lh * 4) = u;
            ushort4 v;
            v.x = f2bf((o1[gg * 4 + 0] + Om[(cidx * 32 + 16 + gg * 4 + 0) * 64 + lane]) * inv);
            v.y = f2bf((o1[gg * 4 + 1] + Om[(cidx * 32 + 16 + gg * 4 + 1) * 64 + lane]) * inv);
            v.z = f2bf((o1[gg * 4 + 2] + Om[(cidx * 32 + 16 + gg * 4 + 2) * 64 + lane]) * inv);
            v.w = f2bf((o1[gg * 4 + 3] + Om[(cidx * 32 + 16 + gg * 4 + 3) * 64 + lane]) * inv);
            *(ushort4*)(obase + 32 + gg * 8 + lh * 4) = v;
        }
    }
#undef STAGE
}

// ---------------- output projection GEMM + bias, f32 out (128x64 tiles) ----------------
// Flat grid 512, XCD 2D swizzle (8m x 8n chunk per XCD).
__global__ __launch_bounds__(256) void gemm_out(
    const unsigned short* __restrict__ ab,
    const unsigned short* __restrict__ wob,
    const float* __restrict__ bo,
    float* __restrict__ out)
{
    __shared__ __align__(16) unsigned short Al[128 * 32];
    __shared__ __align__(16) unsigned short Bl[64 * 32];

    const int bid = blockIdx.x;
    const int xcd = bid & 7;
    const int s = bid >> 3;               // 0..63
    const int i4 = xcd >> 1, k2 = xcd & 1;
    const int m0 = (i4 * 8 + (s >> 3)) * 128;
    const int n0 = (k2 * 8 + (s & 7)) * 64;

    const int tid = threadIdx.x;
    const int lane = tid & 63;
    const int w = tid >> 6;
    const int lr = lane & 15, lg = lane >> 4;

    f32x4 acc[2][4] = {};

    for (int k0 = 0; k0 < 1024; k0 += 32) {
        __syncthreads();
#pragma unroll
        for (int p = 0; p < 2; ++p) {
            const int u = p * 256 + tid;
            const int row = u >> 2, seg = u & 3;
            gload16(ab + (size_t)(m0 + row) * 1024 + k0 + seg * 8, Al + (u & ~63) * 8);
        }
        {
            const int u = tid;
            const int row = u >> 2, seg = u & 3;
            gload16(wob + (size_t)(n0 + row) * 1024 + k0 + seg * 8, Bl + (u & ~63) * 8);
        }
        __syncthreads();
        bf16x8 af[2], bfr[4];
#pragma unroll
        for (int mt = 0; mt < 2; ++mt)
            af[mt] = *(const bf16x8*)(Al + (w * 32 + mt * 16 + lr) * 32 + lg * 8);
#pragma unroll
        for (int nt = 0; nt < 4; ++nt)
            bfr[nt] = *(const bf16x8*)(Bl + (nt * 16 + lr) * 32 + lg * 8);
#pragma unroll
        for (int mt = 0; mt < 2; ++mt)
#pragma unroll
            for (int nt = 0; nt < 4; ++nt)
                acc[mt][nt] = __builtin_amdgcn_mfma_f32_16x16x32_bf16(af[mt], bfr[nt], acc[mt][nt], 0, 0, 0);
    }

#pragma unroll
    for (int mt = 0; mt < 2; ++mt) {
#pragma unroll
        for (int nt = 0; nt < 4; ++nt) {
            const int col = n0 + nt * 16 + lr;
            const float bcol = bo[col];
#pragma unroll
            for (int r = 0; r < 4; ++r) {
                const int mrow = m0 + w * 32 + mt * 16 + lg * 4 + r;
                out[(size_t)mrow * 1024 + col] = acc[mt][nt][r] + bcol;
            }
        }
    }
}

extern "C" void kernel_launch(void* const* d_in, const int* in_sizes, int n_in,
                              void* d_out, int out_size, void* d_ws, size_t ws_size,
                              hipStream_t stream) {
    const float* x    = (const float*)d_in[0];
    const float* cosT = (const float*)d_in[1];
    const float* sinT = (const float*)d_in[2];
    const float* Wq   = (const float*)d_in[3];
    const float* bq   = (const float*)d_in[4];
    const float* Wk   = (const float*)d_in[5];
    const float* bk   = (const float*)d_in[6];
    const float* Wv   = (const float*)d_in[7];
    const float* bv   = (const float*)d_in[8];
    const float* Wo   = (const float*)d_in[9];
    const float* bo   = (const float*)d_in[10];
    float* out = (float*)d_out;

    char* ws = (char*)d_ws;
    unsigned short* xb    = (unsigned short*)(ws + 0);           // 8 MB, dead after gemm_qkv
    unsigned short* attnb = (unsigned short*)(ws + 0);           // overlays xb
    unsigned short* wob   = (unsigned short*)(ws + 8388608);     // 2 MB
    unsigned short* wqb   = (unsigned short*)(ws + 10485760);
    unsigned short* wkb   = (unsigned short*)(ws + 12582912);
    unsigned short* wvb   = (unsigned short*)(ws + 14680064);
    unsigned short* Qb    = (unsigned short*)(ws + 16777216);    // 8 MB
    unsigned short* Kb    = (unsigned short*)(ws + 25165824);    // 8 MB
    unsigned short* Vtg   = (unsigned short*)(ws + 33554432);    // 8.5 MB, [bh][64][VSTRIDE]

    cvt_all<<<dim3(4096, 5), 256, 0, stream>>>(x, Wq, Wk, Wv, Wo, xb, wqb, wkb, wvb, wob);
    gemm_qkv<<<dim3(768), 512, 0, stream>>>(xb, wqb, wkb, wvb, bq, bk, bv,
                                            cosT, sinT, Qb, Kb, Vtg);
    attn_fwd<<<dim3(512), 512, 0, stream>>>(Qb, Kb, Vtg, attnb);
    gemm_out<<<dim3(512), 256, 0, stream>>>(attnb, wob, bo, out);
}

// Round 28
// 105.998 us; speedup vs baseline: 1.0257x; 1.0257x over previous
//
#include <hip/hip_runtime.h>
#include <hip/hip_bf16.h>
#include <cstdint>
#include <cstddef>

typedef __attribute__((ext_vector_type(8))) short bf16x8;
typedef __attribute__((ext_vector_type(4))) float f32x4;
typedef __attribute__((ext_vector_type(16))) float f32x16;

#define SCALE2 0.180336880111112f   // 0.125 * log2(e): softmax in base-2 domain
#define VSTRIDE 2080                // V^T row stride (padded: 4160B = 65 cache lines)

__device__ __forceinline__ unsigned short f2bf(float f) {
    unsigned u = __builtin_bit_cast(unsigned, f);
    unsigned r = (u + 0x7FFFu + ((u >> 16) & 1u)) >> 16;
    return (unsigned short)r;
}

__device__ __forceinline__ void gload16(const unsigned short* g, unsigned short* l) {
    __builtin_amdgcn_global_load_lds(
        (const __attribute__((address_space(1))) unsigned int*)(g),
        (__attribute__((address_space(3))) unsigned int*)(l), 16, 0, 0);
}

// ---------------- merged f32 -> bf16 convert (x + 4 weights) ----------------
__global__ void cvt_all(const float* __restrict__ x,
                        const float* __restrict__ wq, const float* __restrict__ wk,
                        const float* __restrict__ wv, const float* __restrict__ wo,
                        unsigned short* __restrict__ xb,
                        unsigned short* __restrict__ wqb, unsigned short* __restrict__ wkb,
                        unsigned short* __restrict__ wvb, unsigned short* __restrict__ wob)
{
    const int y = blockIdx.y;
    const float* src; unsigned short* dst; int n;
    switch (y) {
        case 0: src = x;  dst = xb;  n = 4194304; break;
        case 1: src = wq; dst = wqb; n = 1048576; break;
        case 2: src = wk; dst = wkb; n = 1048576; break;
        case 3: src = wv; dst = wvb; n = 1048576; break;
        default: src = wo; dst = wob; n = 1048576; break;
    }
    const int i = (blockIdx.x * 256 + threadIdx.x) * 4;
    if (i < n) {
        float4 v = *(const float4*)(src + i);
        ushort4 o;
        o.x = f2bf(v.x); o.y = f2bf(v.y); o.z = f2bf(v.z); o.w = f2bf(v.w);
        *(ushort4*)(dst + i) = o;
    }
}

// ---------------- QKV projection GEMM + bias + RoPE (512 thr, pipelined) -------------
// (unchanged from r25/r26/r27)
__global__ __launch_bounds__(512) void gemm_qkv(
    const unsigned short* __restrict__ xb,
    const unsigned short* __restrict__ wqb,
    const unsigned short* __restrict__ wkb,
    const unsigned short* __restrict__ wvb,
    const float* __restrict__ bq, const float* __restrict__ bk, const float* __restrict__ bv,
    const float* __restrict__ cosT, const float* __restrict__ sinT,
    unsigned short* __restrict__ Qb, unsigned short* __restrict__ Kb, unsigned short* __restrict__ Vtg)
{
    const int bid = blockIdx.x;
    const int xcd = bid & 7;
    const int s = bid >> 3;               // 0..95
    const int i4 = xcd >> 1, k2 = xcd & 1;
    const int z = s >> 5;                 // 0..2
    const int tt = s & 31;                // 0..31
    const int m0 = (i4 * 8 + (tt >> 2)) * 128;
    const int n0 = (k2 * 4 + (tt & 3)) * 128;

    const unsigned short* wb = (z == 0) ? wqb : ((z == 1) ? wkb : wvb);
    const float* bias = (z == 0) ? bq : ((z == 1) ? bk : bv);
    unsigned short* dst = (z == 0) ? Qb : Kb;

    __shared__ __align__(16) unsigned char gsm[49152];   // 3 x (8KB A + 8KB B); Ct alias

    const int tid = threadIdx.x;
    const int lane = tid & 63;
    const int w = tid >> 6;               // 0..7
    const int wr = w >> 2, wc = w & 3;    // 2 x 4 wave grid
    const int lr = lane & 15, lg = lane >> 4;
    const int srow = tid >> 2;            // 0..127
    const int sslot = (tid & 3) ^ (srow & 3);   // pre-swizzled source seg
    const int wdst = (tid & ~63) * 8;           // wave-uniform LDS dest (elements)

    f32x4 acc[4][2] = {};

#define GSTAGE(KK, B)                                                                  \
    {                                                                                  \
        unsigned short* ab_ = (unsigned short*)(gsm + (B) * 16384);                    \
        unsigned short* bb_ = ab_ + 4096;                                              \
        gload16(xb + (size_t)(m0 + srow) * 1024 + (KK) * 32 + sslot * 8, ab_ + wdst);  \
        gload16(wb + (size_t)(n0 + srow) * 1024 + (KK) * 32 + sslot * 8, bb_ + wdst);  \
    }

    GSTAGE(0, 0);
    GSTAGE(1, 1);
    int bsel = 0;
    for (int kk = 0; kk < 32; ++kk) {
        if (kk < 31) asm volatile("s_waitcnt vmcnt(2)" ::: "memory");
        else         asm volatile("s_waitcnt vmcnt(0)" ::: "memory");
        __syncthreads();                       // buf[bsel] staged for all waves
        if (kk + 2 < 32) {
            int b2 = bsel + 2; if (b2 >= 3) b2 -= 3;
            GSTAGE(kk + 2, b2);
        }
        const unsigned short* Al = (const unsigned short*)(gsm + bsel * 16384);
        const unsigned short* Bl = Al + 4096;
        bf16x8 af[4], bfr[2];
#pragma unroll
        for (int mt = 0; mt < 4; ++mt) {
            const int row = wr * 64 + mt * 16 + lr;
            af[mt] = *(const bf16x8*)(Al + row * 32 + (lg ^ (row & 3)) * 8);
        }
#pragma unroll
        for (int nt = 0; nt < 2; ++nt) {
            const int row = wc * 32 + nt * 16 + lr;
            bfr[nt] = *(const bf16x8*)(Bl + row * 32 + (lg ^ (row & 3)) * 8);
        }
        __builtin_amdgcn_s_setprio(1);
#pragma unroll
        for (int mt = 0; mt < 4; ++mt)
#pragma unroll
            for (int nt = 0; nt < 2; ++nt)
                acc[mt][nt] = __builtin_amdgcn_mfma_f32_16x16x32_bf16(af[mt], bfr[nt], acc[mt][nt], 0, 0, 0);
        __builtin_amdgcn_s_setprio(0);
        bsel += 1; if (bsel == 3) bsel = 0;
    }

    // ---- epilogue: regs -> Ct (aliased over staging LDS), coalesced stores ----
    unsigned short* Ct = (unsigned short*)gsm;   // 128 x 136 = 34 KB <= 48 KB
    __syncthreads();                             // all staging reads done
#pragma unroll
    for (int mt = 0; mt < 4; ++mt) {
#pragma unroll
        for (int nt = 0; nt < 2; ++nt) {
            const int coln = wc * 32 + nt * 16 + lr;     // 0..127
            const int col = n0 + coln;
            const float bcol = bias[col];
            const int hd = col & 63;
#pragma unroll
            for (int r = 0; r < 4; ++r) {
                const int rowm = wr * 64 + mt * 16 + lg * 4 + r;   // 0..127
                float v = acc[mt][nt][r] + bcol;
                if (z < 2) {
                    float part = __shfl_xor(v, 1);   // partner col (hd^1), same row
                    const int ttm = (m0 + rowm) & 2047;
                    const int i = hd >> 1;
                    const float cc = cosT[ttm * 32 + i], ss = sinT[ttm * 32 + i];
                    v = (hd & 1) ? (part * ss + v * cc) : (v * cc - part * ss);
                    if (z == 0) v *= SCALE2;
                    Ct[rowm * 136 + coln] = f2bf(v);
                } else {
                    Ct[coln * 136 + rowm] = f2bf(v);   // transposed for V^T store
                }
            }
        }
    }
    __syncthreads();
    if (z < 2) {
#pragma unroll
        for (int p = 0; p < 4; ++p) {
            const int u = p * 512 + tid;                 // < 2048
            const int row = u >> 4, seg = u & 15;
            bf16x8 vv = *(const bf16x8*)(Ct + row * 136 + seg * 8);
            const int mrow = m0 + row;
            const int ttm = mrow & 2047, bb = mrow >> 11;
            const int col = n0 + seg * 8;
            const int h = col >> 6, hd = col & 63;
            *(bf16x8*)(dst + ((size_t)(bb * 16 + h) * 2048 + ttm) * 64 + hd) = vv;
        }
    } else {
        const int bb = m0 >> 11;
#pragma unroll
        for (int p = 0; p < 4; ++p) {
            const int u = p * 512 + tid;                 // < 2048
            const int vrow = u >> 4, seg = u & 15;
            bf16x8 vv = *(const bf16x8*)(Ct + vrow * 136 + seg * 8);
            const int col = n0 + vrow;
            const int h = col >> 6, hd = col & 63;
            const int ttm = (m0 + seg * 8) & 2047;
            *(bf16x8*)(Vtg + ((size_t)(bb * 16 + h) * 64 + hd) * VSTRIDE + ttm) = vv;
        }
    }
#undef GSTAGE
}

// ---------------- Flash attention (causal): quad-chunk blocks + MFMA row-sum --------
// (unchanged from r27)
__global__ __launch_bounds__(512) void attn_fwd(
    const unsigned short* __restrict__ Qb, const unsigned short* __restrict__ Kb,
    const unsigned short* __restrict__ Vtg, unsigned short* __restrict__ attnb)
{
    __shared__ __align__(16) unsigned char smem[65536];  // 4 x (8KB K + 8KB V)

    const int tid = threadIdx.x, lane = tid & 63, w = tid >> 6;
    const int l31 = lane & 31, lh = lane >> 5;
    const int bid = blockIdx.x;
    const int bh = bid & 31;
    const int g = bid >> 5;                  // 0..15
    const int cidx = w >> 1;                 // 0..3
    const int slice = w & 1;                 // tile parity within super
    const int c = (cidx == 0) ? (63 - g) : ((cidx == 1) ? (47 - g) : ((cidx == 2) ? (16 + g) : g));
    const int smax = (63 - g) >> 1;          // block-wide super count driver
    const size_t base = (size_t)bh * 131072;
    const int myq = c * 32 + l31;

    const unsigned short* Kg = Kb + base;
    const unsigned short* Vg = Vtg + (size_t)bh * (64 * VSTRIDE);

    bf16x8 qf[4];
#pragma unroll
    for (int s = 0; s < 4; ++s)
        qf[s] = *(const bf16x8*)(Qb + base + (size_t)myq * 64 + s * 16 + lh * 8);

    bf16x8 ones;
#pragma unroll
    for (int j = 0; j < 8; ++j) ones[j] = (short)0x3F80;   // 1.0 bf16

    f32x16 o0 = {}, o1 = {}, smacc = {};

    // STAGE super-tile S: 512 threads, 1 K-load + 1 V-load each (16B), pre-swizzled src.
#define STAGE(S, B)                                                                   \
    {                                                                                 \
        unsigned short* kb_ = (unsigned short*)(smem + (B) * 16384);                  \
        unsigned short* vb_ = (unsigned short*)(smem + (B) * 16384 + 8192);           \
        const int row = tid >> 3, ss = (tid & 7) ^ (row & 7);                         \
        gload16(Kg + (size_t)((S) * 64 + row) * 64 + ss * 8, kb_ + (tid & ~63) * 8);  \
        gload16(Vg + (size_t)row * VSTRIDE + (S) * 64 + ss * 8, vb_ + (tid & ~63) * 8);\
    }

    STAGE(0, 0);
    STAGE(1, 1);
    if (smax >= 2) STAGE(2, 2);
    for (int s = 0; s <= smax; ++s) {
        if (s + 2 <= smax)      asm volatile("s_waitcnt vmcnt(4)" ::: "memory");
        else if (s + 1 <= smax) asm volatile("s_waitcnt vmcnt(2)" ::: "memory");
        else                    asm volatile("s_waitcnt vmcnt(0)" ::: "memory");
        __syncthreads();                       // buf[s&3] ready for all waves
        if (s + 3 <= smax) STAGE(s + 3, (s + 3) & 3);
        const int t = 2 * s + slice;
        if (t <= c) {
            const unsigned short* Kc = (const unsigned short*)(smem + (s & 3) * 16384);
            const unsigned short* Vc = Kc + 4096;   // +8192 bytes (element pointer)
            const int kvb = t * 32;
            const int sw = l31 & 7;
            const int roff = slice * 32 + l31;

            bf16x8 kf0 = *(const bf16x8*)(Kc + roff * 64 + ((0 + lh) ^ sw) * 8);
            bf16x8 kf1 = *(const bf16x8*)(Kc + roff * 64 + ((2 + lh) ^ sw) * 8);
            bf16x8 kf2 = *(const bf16x8*)(Kc + roff * 64 + ((4 + lh) ^ sw) * 8);
            bf16x8 kf3 = *(const bf16x8*)(Kc + roff * 64 + ((6 + lh) ^ sw) * 8);

            f32x16 st = {};
            __builtin_amdgcn_s_setprio(1);
            st = __builtin_amdgcn_mfma_f32_32x32x16_bf16(kf0, qf[0], st, 0, 0, 0);
            st = __builtin_amdgcn_mfma_f32_32x32x16_bf16(kf1, qf[1], st, 0, 0, 0);
            st = __builtin_amdgcn_mfma_f32_32x32x16_bf16(kf2, qf[2], st, 0, 0, 0);
            st = __builtin_amdgcn_mfma_f32_32x32x16_bf16(kf3, qf[3], st, 0, 0, 0);
            __builtin_amdgcn_s_setprio(0);

            if (t == c) {
#pragma unroll
                for (int r = 0; r < 16; ++r) {
                    const int kv = kvb + (r & 3) + 8 * (r >> 2) + 4 * lh;
                    st[r] = (kv <= myq) ? st[r] : -1e30f;
                }
            }
#pragma unroll
            for (int r = 0; r < 16; ++r) st[r] = exp2f(st[r]);

            unsigned pw0, pw1, pw2, pw3, pw4, pw5, pw6, pw7;
            {
                unsigned a0, a1, b0, b1;
                asm("v_cvt_pk_bf16_f32 %0, %1, %2" : "=v"(a0) : "v"(st[0]), "v"(st[1]));
                asm("v_cvt_pk_bf16_f32 %0, %1, %2" : "=v"(a1) : "v"(st[2]), "v"(st[3]));
                asm("v_cvt_pk_bf16_f32 %0, %1, %2" : "=v"(b0) : "v"(st[4]), "v"(st[5]));
                asm("v_cvt_pk_bf16_f32 %0, %1, %2" : "=v"(b1) : "v"(st[6]), "v"(st[7]));
                asm("v_permlane32_swap_b32 %0, %1" : "+v"(a0), "+v"(b0));
                asm("v_permlane32_swap_b32 %0, %1" : "+v"(a1), "+v"(b1));
                pw0 = a0; pw1 = a1; pw2 = b0; pw3 = b1;
            }
            {
                unsigned a0, a1, b0, b1;
                asm("v_cvt_pk_bf16_f32 %0, %1, %2" : "=v"(a0) : "v"(st[8]), "v"(st[9]));
                asm("v_cvt_pk_bf16_f32 %0, %1, %2" : "=v"(a1) : "v"(st[10]), "v"(st[11]));
                asm("v_cvt_pk_bf16_f32 %0, %1, %2" : "=v"(b0) : "v"(st[12]), "v"(st[13]));
                asm("v_cvt_pk_bf16_f32 %0, %1, %2" : "=v"(b1) : "v"(st[14]), "v"(st[15]));
                asm("v_permlane32_swap_b32 %0, %1" : "+v"(a0), "+v"(b0));
                asm("v_permlane32_swap_b32 %0, %1" : "+v"(a1), "+v"(b1));
                pw4 = a0; pw5 = a1; pw6 = b0; pw7 = b1;
            }

            const int vs0 = (slice * 4 + lh) ^ sw;
            const int vs1 = (slice * 4 + 2 + lh) ^ sw;
            bf16x8 vf00 = *(const bf16x8*)(Vc + l31 * 64 + vs0 * 8);
            bf16x8 vf01 = *(const bf16x8*)(Vc + l31 * 64 + vs1 * 8);
            bf16x8 vf10 = *(const bf16x8*)(Vc + (32 + l31) * 64 + vs0 * 8);
            bf16x8 vf11 = *(const bf16x8*)(Vc + (32 + l31) * 64 + vs1 * 8);

            uint4 h0 = make_uint4(pw0, pw1, pw2, pw3);
            uint4 h1 = make_uint4(pw4, pw5, pw6, pw7);
            bf16x8 pf0 = __builtin_bit_cast(bf16x8, h0);
            bf16x8 pf1 = __builtin_bit_cast(bf16x8, h1);
            __builtin_amdgcn_s_setprio(1);
            o0 = __builtin_amdgcn_mfma_f32_32x32x16_bf16(vf00, pf0, o0, 0, 0, 0);
            o1 = __builtin_amdgcn_mfma_f32_32x32x16_bf16(vf10, pf0, o1, 0, 0, 0);
            smacc = __builtin_amdgcn_mfma_f32_32x32x16_bf16(ones, pf0, smacc, 0, 0, 0);
            o0 = __builtin_amdgcn_mfma_f32_32x32x16_bf16(vf01, pf1, o0, 0, 0, 0);
            o1 = __builtin_amdgcn_mfma_f32_32x32x16_bf16(vf11, pf1, o1, 0, 0, 0);
            smacc = __builtin_amdgcn_mfma_f32_32x32x16_bf16(ones, pf1, smacc, 0, 0, 0);
            __builtin_amdgcn_s_setprio(0);
        }
    }

    const float sm = smacc[0];   // every lane: row (4*lh) of ones@P^T = full kv-sum

    // ---- per-chunk partner-slice sum-merge (staging LDS re-aliased) ----
    float* Om = (float*)smem;                 // [4][32][64] = 32 KB
    float* Ms = (float*)(smem + 32768);       // [4][64]
    __syncthreads();                          // all staging reads/writes done
    if (slice == 1) {
#pragma unroll
        for (int i = 0; i < 16; ++i) Om[(cidx * 32 + i) * 64 + lane] = o0[i];
#pragma unroll
        for (int i = 0; i < 16; ++i) Om[(cidx * 32 + 16 + i) * 64 + lane] = o1[i];
        Ms[cidx * 64 + lane] = sm;
    }
    __syncthreads();
    if (slice == 0) {
        const float s = sm + Ms[cidx * 64 + lane];
        const float inv = 1.f / s;
        const int b = bh >> 4, h = bh & 15;
        unsigned short* obase = attnb + ((size_t)(b * 2048 + myq)) * 1024 + h * 64;
#pragma unroll
        for (int gg = 0; gg < 4; ++gg) {
            ushort4 u;
            u.x = f2bf((o0[gg * 4 + 0] + Om[(cidx * 32 + gg * 4 + 0) * 64 + lane]) * inv);
            u.y = f2bf((o0[gg * 4 + 1] + Om[(cidx * 32 + gg * 4 + 1) * 64 + lane]) * inv);
            u.z = f2bf((o0[gg * 4 + 2] + Om[(cidx * 32 + gg * 4 + 2) * 64 + lane]) * inv);
            u.w = f2bf((o0[gg * 4 + 3] + Om[(cidx * 32 + gg * 4 + 3) * 64 + lane]) * inv);
            *(ushort4*)(obase + gg * 8 + lh * 4) = u;
            ushort4 v;
            v.x = f2bf((o1[gg * 4 + 0] + Om[(cidx * 32 + 16 + gg * 4 + 0) * 64 + lane]) * inv);
            v.y = f2bf((o1[gg * 4 + 1] + Om[(cidx * 32 + 16 + gg * 4 + 1) * 64 + lane]) * inv);
            v.z = f2bf((o1[gg * 4 + 2] + Om[(cidx * 32 + 16 + gg * 4 + 2) * 64 + lane]) * inv);
            v.w = f2bf((o1[gg * 4 + 3] + Om[(cidx * 32 + 16 + gg * 4 + 3) * 64 + lane]) * inv);
            *(ushort4*)(obase + 32 + gg * 8 + lh * 4) = v;
        }
    }
#undef STAGE
}

// ---------------- output projection GEMM + bias, f32 out (128x64, PIPELINED) --------
// r24's proven 3-buffer counted-vmcnt K-loop ported: 3 x 12KB buffers (A 8KB | B 4KB),
// 3 loads/thread/stage -> wait vmcnt(3) mid-loop (never 0), ONE barrier per K-step,
// XOR-swizzled staging (source seg^(row&3), read lg^(row&3)). Epilogue unchanged.
__global__ __launch_bounds__(256) void gemm_out(
    const unsigned short* __restrict__ ab,
    const unsigned short* __restrict__ wob,
    const float* __restrict__ bo,
    float* __restrict__ out)
{
    __shared__ __align__(16) unsigned char osm[36864];   // 3 x (8KB A + 4KB B)

    const int bid = blockIdx.x;
    const int xcd = bid & 7;
    const int s = bid >> 3;               // 0..63
    const int i4 = xcd >> 1, k2 = xcd & 1;
    const int m0 = (i4 * 8 + (s >> 3)) * 128;
    const int n0 = (k2 * 8 + (s & 7)) * 64;

    const int tid = threadIdx.x;
    const int lane = tid & 63;
    const int w = tid >> 6;
    const int lr = lane & 15, lg = lane >> 4;
    const int srow = tid >> 2, sseg = tid & 3;

    f32x4 acc[2][4] = {};

#define OSTAGE(KK, B)                                                                   \
    {                                                                                   \
        unsigned short* ab_ = (unsigned short*)(osm + (B) * 12288);                     \
        unsigned short* bb_ = ab_ + 4096;                                               \
        _Pragma("unroll")                                                               \
        for (int p = 0; p < 2; ++p) {                                                   \
            const int u = p * 256 + tid;                                                \
            const int row = u >> 2, ss2 = (u & 3) ^ (row & 3);                          \
            gload16(ab + (size_t)(m0 + row) * 1024 + (KK) * 32 + ss2 * 8, ab_ + (u & ~63) * 8); \
        }                                                                               \
        {                                                                               \
            const int ss2 = sseg ^ (srow & 3);                                          \
            gload16(wob + (size_t)(n0 + srow) * 1024 + (KK) * 32 + ss2 * 8, bb_ + (tid & ~63) * 8); \
        }                                                                               \
    }

    OSTAGE(0, 0);
    OSTAGE(1, 1);
    int bsel = 0;
    for (int kk = 0; kk < 32; ++kk) {
        if (kk < 31) asm volatile("s_waitcnt vmcnt(3)" ::: "memory");
        else         asm volatile("s_waitcnt vmcnt(0)" ::: "memory");
        __syncthreads();                       // buf[bsel] staged for all waves
        if (kk + 2 < 32) {
            int b2 = bsel + 2; if (b2 >= 3) b2 -= 3;
            OSTAGE(kk + 2, b2);
        }
        const unsigned short* Al = (const unsigned short*)(osm + bsel * 12288);
        const unsigned short* Bl = Al + 4096;
        bf16x8 af[2], bfr[4];
#pragma unroll
        for (int mt = 0; mt < 2; ++mt) {
            const int row = w * 32 + mt * 16 + lr;
            af[mt] = *(const bf16x8*)(Al + row * 32 + (lg ^ (row & 3)) * 8);
        }
#pragma unroll
        for (int nt = 0; nt < 4; ++nt) {
            const int row = nt * 16 + lr;
            bfr[nt] = *(const bf16x8*)(Bl + row * 32 + (lg ^ (row & 3)) * 8);
        }
        __builtin_amdgcn_s_setprio(1);
#pragma unroll
        for (int mt = 0; mt < 2; ++mt)
#pragma unroll
            for (int nt = 0; nt < 4; ++nt)
                acc[mt][nt] = __builtin_amdgcn_mfma_f32_16x16x32_bf16(af[mt], bfr[nt], acc[mt][nt], 0, 0, 0);
        __builtin_amdgcn_s_setprio(0);
        bsel += 1; if (bsel == 3) bsel = 0;
    }

#pragma unroll
    for (int mt = 0; mt < 2; ++mt) {
#pragma unroll
        for (int nt = 0; nt < 4; ++nt) {
            const int col = n0 + nt * 16 + lr;
            const float bcol = bo[col];
#pragma unroll
            for (int r = 0; r < 4; ++r) {
                const int mrow = m0 + w * 32 + mt * 16 + lg * 4 + r;
                out[(size_t)mrow * 1024 + col] = acc[mt][nt][r] + bcol;
            }
        }
    }
#undef OSTAGE
}

extern "C" void kernel_launch(void* const* d_in, const int* in_sizes, int n_in,
                              void* d_out, int out_size, void* d_ws, size_t ws_size,
                              hipStream_t stream) {
    const float* x    = (const float*)d_in[0];
    const float* cosT = (const float*)d_in[1];
    const float* sinT = (const float*)d_in[2];
    const float* Wq   = (const float*)d_in[3];
    const float* bq   = (const float*)d_in[4];
    const float* Wk   = (const float*)d_in[5];
    const float* bk   = (const float*)d_in[6];
    const float* Wv   = (const float*)d_in[7];
    const float* bv   = (const float*)d_in[8];
    const float* Wo   = (const float*)d_in[9];
    const float* bo   = (const float*)d_in[10];
    float* out = (float*)d_out;

    char* ws = (char*)d_ws;
    unsigned short* xb    = (unsigned short*)(ws + 0);           // 8 MB, dead after gemm_qkv
    unsigned short* attnb = (unsigned short*)(ws + 0);           // overlays xb
    unsigned short* wob   = (unsigned short*)(ws + 8388608);     // 2 MB
    unsigned short* wqb   = (unsigned short*)(ws + 10485760);
    unsigned short* wkb   = (unsigned short*)(ws + 12582912);
    unsigned short* wvb   = (unsigned short*)(ws + 14680064);
    unsigned short* Qb    = (unsigned short*)(ws + 16777216);    // 8 MB
    unsigned short* Kb    = (unsigned short*)(ws + 25165824);    // 8 MB
    unsigned short* Vtg   = (unsigned short*)(ws + 33554432);    // 8.5 MB, [bh][64][VSTRIDE]

    cvt_all<<<dim3(4096, 5), 256, 0, stream>>>(x, Wq, Wk, Wv, Wo, xb, wqb, wkb, wvb, wob);
    gemm_qkv<<<dim3(768), 512, 0, stream>>>(xb, wqb, wkb, wvb, bq, bk, bv,
                                            cosT, sinT, Qb, Kb, Vtg);
    attn_fwd<<<dim3(512), 512, 0, stream>>>(Qb, Kb, Vtg, attnb);
    gemm_out<<<dim3(512), 256, 0, stream>>>(attnb, wob, bo, out);
}